// Round 10
// baseline (688.794 us; speedup 1.0000x reference)
//
#include <hip/hip_runtime.h>

#define B_   32
#define HW_  196
#define C_   512
#define M_   (B_*HW_)    // 6272
#define HID_ 128
#define NBLK 18
#define NGRID 196        // one block per 32-row stripe
#define NTHR  512        // 8 waves; each wave owns 64 output cols
#define LDP   520        // padded LDS row stride (halfs): 1040 B, 16B-aligned

typedef _Float16 f16;
typedef _Float16 f16x8 __attribute__((ext_vector_type(8)));
typedef float    f32x4 __attribute__((ext_vector_type(4)));

// gelu(tanh approx) == x * sigmoid(2*0.79788456*(x+0.044715x^3)) exactly
__device__ __forceinline__ float gelu_f(float x) {
    float z = 0.7978845608028654f * (x + 0.044715f * x * x * x);
    return x / (1.f + __expf(-2.f * z));
}

// arrival-counter + release-flag grid barrier
__device__ __forceinline__ void grid_barrier(unsigned* cnt, unsigned* rel, unsigned epoch) {
    __syncthreads();
    if (threadIdx.x == 0) {
        __threadfence();
        unsigned old = atomicAdd(cnt, 1u);
        if (old == epoch * NGRID - 1) {
            __hip_atomic_store(rel, epoch, __ATOMIC_RELEASE, __HIP_MEMORY_SCOPE_AGENT);
        } else {
            while (__hip_atomic_load(rel, __ATOMIC_ACQUIRE, __HIP_MEMORY_SCOPE_AGENT) < epoch)
                __builtin_amdgcn_s_sleep(8);
        }
        __threadfence();
    }
    __syncthreads();
}

// ---------- weights: fp32 [blk][k][n] -> fp16 transposed [blk][n][k] ----------
__global__ __launch_bounds__(256) void conv_w(const float* __restrict__ W,
                                              f16* __restrict__ Wt) {
    __shared__ f16 sh[64][72];
    const int blk = blockIdx.z, k0 = blockIdx.x * 64, n0 = blockIdx.y * 64;
    const int tid = threadIdx.x;
    const float* Wb = W + (size_t)blk * C_ * C_;
    #pragma unroll
    for (int i = 0; i < 4; ++i) {
        int s = tid + i * 256, r = s >> 4, c4 = (s & 15) << 2;
        float4 v = *(const float4*)&Wb[(size_t)(k0 + r) * C_ + n0 + c4];
        sh[r][c4 + 0] = (f16)v.x; sh[r][c4 + 1] = (f16)v.y;
        sh[r][c4 + 2] = (f16)v.z; sh[r][c4 + 3] = (f16)v.w;
    }
    __syncthreads();
    #pragma unroll
    for (int i = 0; i < 2; ++i) {
        int s = tid + i * 256, r = s >> 3, c8 = (s & 7) << 3;
        f16x8 o;
        #pragma unroll
        for (int j = 0; j < 8; ++j) o[j] = sh[c8 + j][r];
        *(f16x8*)&Wt[(size_t)blk * C_ * C_ + (size_t)(n0 + r) * C_ + k0 + c8] = o;
    }
}

// ---------- persistent: 18 layers, activations resident in LDS ----------
// Block owns rows [blk*32, +32). 8 waves x 64 cols; per wave 2x4 frags of
// 16x16x32. W read as register B-frags from L2, ring-prefetched 4 deep.
__global__ __launch_bounds__(NTHR, 2) void stage_persistent(
    const float* __restrict__ x, const f16* __restrict__ Wt,
    const float* __restrict__ ball,
    const float* __restrict__ fc1w, const float* __restrict__ fc1b,
    const float* __restrict__ fc2w, const float* __restrict__ fc2b,
    const float* __restrict__ gammas,
    f16* __restrict__ Anc0, f16* __restrict__ Anc1, f16* __restrict__ Anc2,
    float* __restrict__ pooled, float* __restrict__ gates,
    unsigned* __restrict__ cnt, unsigned* __restrict__ rel,
    float* __restrict__ out)
{
    __shared__ f16 act[2][32][LDP];     // 66,560 B ping-pong activation stripe
    __shared__ float spG[C_];
    __shared__ float shG[HID_];

    const int tid = threadIdx.x, blk = blockIdx.x;
    const int lane = tid & 63, wave = tid >> 6;
    const int m15 = lane & 15, q = lane >> 4;
    const int row0 = blk * 32;
    const int ncol0 = wave * 64;

    // layer-0 input: x fp32 rows -> act[0] fp16
    for (int ch = tid; ch < 32 * 128; ch += NTHR) {
        int r = ch >> 7, c4 = (ch & 127) << 2;
        float4 v = *(const float4*)&x[(size_t)(row0 + r) * C_ + c4];
        act[0][r][c4 + 0] = (f16)v.x; act[0][r][c4 + 1] = (f16)v.y;
        act[0][r][c4 + 2] = (f16)v.z; act[0][r][c4 + 3] = (f16)v.w;
    }
    __syncthreads();

    unsigned epoch = 0;

    for (int L = 0; L < NBLK; ++L) {
        const int cur = L & 1, nxt = cur ^ 1;
        const f16* WL = Wt + (size_t)L * C_ * C_;
        const float* bias = ball + (size_t)L * C_;

        f32x4 acc[2][4];
        #pragma unroll
        for (int i = 0; i < 2; ++i)
            #pragma unroll
            for (int j = 0; j < 4; ++j) acc[i][j] = (f32x4)0.f;

        const f16* wp[4];
        #pragma unroll
        for (int j = 0; j < 4; ++j)
            wp[j] = WL + (size_t)(ncol0 + j * 16 + m15) * C_ + q * 8;

        // W ring prefetch, depth 4: slots kt&3; k-steps 0..3 preloaded
        f16x8 bfr[4][4];
        #pragma unroll
        for (int p = 0; p < 4; ++p)
            #pragma unroll
            for (int j = 0; j < 4; ++j)
                bfr[p][j] = *(const f16x8*)(wp[j] + p * 32);

        // af double buffer: k-step 0 preloaded
        f16x8 af[2][2];
        #pragma unroll
        for (int i = 0; i < 2; ++i)
            af[0][i] = *(const f16x8*)&act[cur][i * 16 + m15][q * 8];

        #pragma unroll
        for (int kt = 0; kt < 16; ++kt) {
            const int pb = kt & 3, ab = kt & 1;
            if (kt + 1 < 16) {
                #pragma unroll
                for (int i = 0; i < 2; ++i)
                    af[ab ^ 1][i] = *(const f16x8*)&act[cur][i * 16 + m15][(kt + 1) * 32 + q * 8];
            }
            #pragma unroll
            for (int i = 0; i < 2; ++i)
                #pragma unroll
                for (int j = 0; j < 4; ++j)
                    acc[i][j] = __builtin_amdgcn_mfma_f32_16x16x32_f16(af[ab][i], bfr[pb][j], acc[i][j], 0, 0, 0);
            if (kt + 4 < 16) {           // refill the slot just consumed
                #pragma unroll
                for (int j = 0; j < 4; ++j)
                    bfr[pb][j] = *(const f16x8*)(wp[j] + (kt + 4) * 32);
            }
        }

        // epilogue (C/D layout col=lane&15, row=quad*4+reg): gelu -> act[nxt]
        float bcol[4];
        #pragma unroll
        for (int j = 0; j < 4; ++j) bcol[j] = bias[ncol0 + j * 16 + m15];
        #pragma unroll
        for (int i = 0; i < 2; ++i)
            #pragma unroll
            for (int r = 0; r < 4; ++r) {
                int row = i * 16 + q * 4 + r;
                #pragma unroll
                for (int j = 0; j < 4; ++j)
                    act[nxt][row][ncol0 + j * 16 + m15] = (f16)gelu_f(acc[i][j][r] + bcol[j]);
            }
        __syncthreads();

        // anchor layers: spill stripe to global (row-local; same block reads back)
        int ai = (L == 1) ? 0 : (L == 4) ? 1 : (L == 9) ? 2 : -1;
        if (ai >= 0) {
            f16* dst = (ai == 0 ? Anc0 : ai == 1 ? Anc1 : Anc2) + (size_t)row0 * C_;
            for (int ch = tid; ch < 32 * 64; ch += NTHR) {
                int r = ch >> 6, c8 = (ch & 63) << 3;
                *(f16x8*)&dst[(size_t)r * C_ + c8] = *(const f16x8*)&act[nxt][r][c8];
            }
        }

        int t = (L == 11) ? 0 : (L == 14) ? 1 : (L == 17) ? 2 : -1;
        if (t >= 0) {
            // pool partials: this stripe spans <=2 batches
            {
                int c = tid;                         // NTHR == C_
                int b0 = row0 / HW_;
                int rs = (b0 + 1) * HW_ - row0; if (rs > 32) rs = 32;
                float s0 = 0.f, s1 = 0.f;
                for (int r = 0; r < rs; ++r)  s0 += (float)act[nxt][r][c];
                for (int r = rs; r < 32; ++r) s1 += (float)act[nxt][r][c];
                atomicAdd(&pooled[(size_t)(t * B_ + b0) * C_ + c], s0);
                if (rs < 32) atomicAdd(&pooled[(size_t)(t * B_ + b0 + 1) * C_ + c], s1);
            }
            grid_barrier(cnt, rel, ++epoch);

            // gate MLP + softmax: blocks 0..31, one batch each
            if (blk < B_) {
                int b = blk;
                spG[tid] = pooled[(size_t)(t * B_ + b) * C_ + tid] * (1.f / 196.f);
                __syncthreads();
                if (tid < HID_) {
                    const float* w = fc1w + (size_t)t * C_ * HID_ + tid;
                    float s = fc1b[t * HID_ + tid];
                    for (int c = 0; c < C_; ++c) s += spG[c] * w[(size_t)c * HID_];
                    shG[tid] = gelu_f(s);
                }
                __syncthreads();
                {
                    int c = tid;
                    const float* w2 = fc2w + (size_t)t * HID_ * (3 * C_) + c;
                    float l0 = fc2b[t * 3 * C_ + c];
                    float l1 = fc2b[t * 3 * C_ + C_ + c];
                    float l2 = fc2b[t * 3 * C_ + 2 * C_ + c];
                    for (int j = 0; j < HID_; ++j) {
                        float h = shG[j];
                        const float* rw = w2 + (size_t)j * 3 * C_;
                        l0 += h * rw[0]; l1 += h * rw[C_]; l2 += h * rw[2 * C_];
                    }
                    float m = fmaxf(l0, fmaxf(l1, l2));
                    float e0 = expf(l0 - m), e1 = expf(l1 - m), e2 = expf(l2 - m);
                    float inv = 1.f / (e0 + e1 + e2);
                    gates[(size_t)b * 3 * C_ + c]          = e0 * inv;
                    gates[(size_t)b * 3 * C_ + C_ + c]     = e1 * inv;
                    gates[(size_t)b * 3 * C_ + 2 * C_ + c] = e2 * inv;
                }
            }
            grid_barrier(cnt, rel, ++epoch);

            // routed add (row-local): act[nxt] += gamma * sum_a g[b,a,c]*anchor
            {
                float gamma = gammas[t];
                const f16* a0 = Anc0 + (size_t)row0 * C_;
                const f16* a1 = Anc1 + (size_t)row0 * C_;
                const f16* a2 = Anc2 + (size_t)row0 * C_;
                for (int ch = tid; ch < 32 * 64; ch += NTHR) {
                    int r = ch >> 6, c8 = (ch & 63) << 3;
                    int b = (row0 + r) / HW_;
                    const float* g = gates + (size_t)b * 3 * C_ + c8;
                    f16x8 xv = *(const f16x8*)&act[nxt][r][c8];
                    f16x8 v0 = *(const f16x8*)&a0[(size_t)r * C_ + c8];
                    f16x8 v1 = *(const f16x8*)&a1[(size_t)r * C_ + c8];
                    f16x8 v2 = *(const f16x8*)&a2[(size_t)r * C_ + c8];
                    float rr[8];
                    #pragma unroll
                    for (int e = 0; e < 8; ++e)
                        rr[e] = (float)xv[e] + gamma * (g[e] * (float)v0[e]
                              + g[C_ + e] * (float)v1[e] + g[2 * C_ + e] * (float)v2[e]);
                    if (t == 2) {
                        size_t o = (size_t)(row0 + r) * C_ + c8;
                        *(float4*)&out[o]     = make_float4(rr[0], rr[1], rr[2], rr[3]);
                        *(float4*)&out[o + 4] = make_float4(rr[4], rr[5], rr[6], rr[7]);
                    } else {
                        f16x8 o8;
                        #pragma unroll
                        for (int e = 0; e < 8; ++e) o8[e] = (f16)rr[e];
                        *(f16x8*)&act[nxt][r][c8] = o8;
                    }
                }
            }
            __syncthreads();
        }
    }
}

extern "C" void kernel_launch(void* const* d_in, const int* in_sizes, int n_in,
                              void* d_out, int out_size, void* d_ws, size_t ws_size,
                              hipStream_t stream)
{
    const float* x      = (const float*)d_in[0];
    const float* blockw = (const float*)d_in[1];
    const float* blockb = (const float*)d_in[2];
    const float* fc1w   = (const float*)d_in[3];
    const float* fc1b   = (const float*)d_in[4];
    const float* fc2w   = (const float*)d_in[5];
    const float* fc2b   = (const float*)d_in[6];
    const float* gammas = (const float*)d_in[7];
    float* out = (float*)d_out;

    const size_t NB = (size_t)M_ * C_;            // 3,211,264 elems
    f16* Wt   = (f16*)d_ws;                        // 9.44 MB
    f16* Anc0 = Wt + (size_t)NBLK * C_ * C_;       // 6.42 MB each
    f16* Anc1 = Anc0 + NB;
    f16* Anc2 = Anc1 + NB;
    float* pooled = (float*)(Anc2 + NB);           // [3][32][512]
    float* gates  = pooled + 3 * B_ * C_;          // [32][3][512]
    unsigned* cnt = (unsigned*)(gates + B_ * 3 * C_);
    unsigned* rel = cnt + 32;                      // separate cache line

    (void)hipMemsetAsync(pooled, 0, (size_t)(3 * B_ * C_ + B_ * 3 * C_) * 4 + 256, stream);
    conv_w<<<dim3(8, 8, NBLK), 256, 0, stream>>>(blockw, Wt);

    stage_persistent<<<NGRID, NTHR, 0, stream>>>(
        x, Wt, blockb, fc1w, fc1b, fc2w, fc2b, gammas,
        Anc0, Anc1, Anc2, pooled, gates, cnt, rel, out);
}

// Round 11
// 683.943 us; speedup vs baseline: 1.0071x; 1.0071x over previous
//
#include <hip/hip_runtime.h>

#define B_   32
#define HW_  196
#define C_   512
#define M_   (B_*HW_)    // 6272
#define HID_ 128
#define NBLK 18
#define NGRID 196        // one block per 32-row stripe
#define NTHR  512        // 8 waves; each wave owns 64 output cols
#define LDP   520        // padded LDS row stride (halfs)
#define DEPTH 6          // W-load ring depth (k-steps in flight)

typedef _Float16 f16;
typedef _Float16 f16x8 __attribute__((ext_vector_type(8)));
typedef float    f32x4 __attribute__((ext_vector_type(4)));

// gelu(tanh approx) == x * sigmoid(2*0.79788456*(x+0.044715x^3)) exactly
__device__ __forceinline__ float gelu_f(float x) {
    float z = 0.7978845608028654f * (x + 0.044715f * x * x * x);
    return x / (1.f + __expf(-2.f * z));
}

// arrival-counter + release-flag grid barrier
__device__ __forceinline__ void grid_barrier(unsigned* cnt, unsigned* rel, unsigned epoch) {
    __syncthreads();
    if (threadIdx.x == 0) {
        __threadfence();
        unsigned old = atomicAdd(cnt, 1u);
        if (old == epoch * NGRID - 1) {
            __hip_atomic_store(rel, epoch, __ATOMIC_RELEASE, __HIP_MEMORY_SCOPE_AGENT);
        } else {
            while (__hip_atomic_load(rel, __ATOMIC_ACQUIRE, __HIP_MEMORY_SCOPE_AGENT) < epoch)
                __builtin_amdgcn_s_sleep(8);
        }
        __threadfence();
    }
    __syncthreads();
}

// ---------- weights: fp32 [blk][k][n] -> fp16 transposed [blk][n][k] ----------
__global__ __launch_bounds__(256) void conv_w(const float* __restrict__ W,
                                              f16* __restrict__ Wt) {
    __shared__ f16 sh[64][72];
    const int blk = blockIdx.z, k0 = blockIdx.x * 64, n0 = blockIdx.y * 64;
    const int tid = threadIdx.x;
    const float* Wb = W + (size_t)blk * C_ * C_;
    #pragma unroll
    for (int i = 0; i < 4; ++i) {
        int s = tid + i * 256, r = s >> 4, c4 = (s & 15) << 2;
        float4 v = *(const float4*)&Wb[(size_t)(k0 + r) * C_ + n0 + c4];
        sh[r][c4 + 0] = (f16)v.x; sh[r][c4 + 1] = (f16)v.y;
        sh[r][c4 + 2] = (f16)v.z; sh[r][c4 + 3] = (f16)v.w;
    }
    __syncthreads();
    #pragma unroll
    for (int i = 0; i < 2; ++i) {
        int s = tid + i * 256, r = s >> 3, c8 = (s & 7) << 3;
        f16x8 o;
        #pragma unroll
        for (int j = 0; j < 8; ++j) o[j] = sh[c8 + j][r];
        *(f16x8*)&Wt[(size_t)blk * C_ * C_ + (size_t)(n0 + r) * C_ + k0 + c8] = o;
    }
}

// ---------- persistent: 18 layers, activations resident in LDS ----------
// W loads are inline-asm global_load_dwordx4 with explicit vmcnt pipelining
// (ring depth 6 k-steps = 24 loads in flight) -- compiler cannot collapse it.
__global__ __launch_bounds__(NTHR, 2) void stage_persistent(
    const float* __restrict__ x, const f16* __restrict__ Wt,
    const float* __restrict__ ball,
    const float* __restrict__ fc1w, const float* __restrict__ fc1b,
    const float* __restrict__ fc2w, const float* __restrict__ fc2b,
    const float* __restrict__ gammas,
    f16* __restrict__ Anc0, f16* __restrict__ Anc1, f16* __restrict__ Anc2,
    float* __restrict__ pooled, float* __restrict__ gates,
    unsigned* __restrict__ cnt, unsigned* __restrict__ rel,
    float* __restrict__ out)
{
    __shared__ f16 act[2][32][LDP];     // 66,560 B ping-pong activation stripe
    __shared__ float spG[C_];
    __shared__ float shG[HID_];

    const int tid = threadIdx.x, blk = blockIdx.x;
    const int lane = tid & 63, wave = tid >> 6;
    const int m15 = lane & 15, q = lane >> 4;
    const int row0 = blk * 32;
    const int ncol0 = wave * 64;

    // layer-0 input: x fp32 rows -> act[0] fp16
    for (int ch = tid; ch < 32 * 128; ch += NTHR) {
        int r = ch >> 7, c4 = (ch & 127) << 2;
        float4 v = *(const float4*)&x[(size_t)(row0 + r) * C_ + c4];
        act[0][r][c4 + 0] = (f16)v.x; act[0][r][c4 + 1] = (f16)v.y;
        act[0][r][c4 + 2] = (f16)v.z; act[0][r][c4 + 3] = (f16)v.w;
    }
    __syncthreads();

    unsigned epoch = 0;

    for (int L = 0; L < NBLK; ++L) {
        const int cur = L & 1, nxt = cur ^ 1;
        const f16* WL = Wt + (size_t)L * C_ * C_;
        const float* bias = ball + (size_t)L * C_;

        f32x4 acc[2][4];
        #pragma unroll
        for (int i = 0; i < 2; ++i)
            #pragma unroll
            for (int j = 0; j < 4; ++j) acc[i][j] = (f32x4)0.f;

        // frag-row base pointers; per-k-step advance is a compile-time offset:
        // (kt*32 halfs = kt*64 bytes, max 960 -- fits 13-bit signed offset)
        const f16* wb[4];
        #pragma unroll
        for (int j = 0; j < 4; ++j)
            wb[j] = WL + (size_t)(ncol0 + j * 16 + m15) * C_ + q * 8;

        // drain all prior vmem so our vmcnt counting is exact
        asm volatile("s_waitcnt vmcnt(0)" ::: "memory");

        // W ring: issue k-steps 0..DEPTH-1 (24 loads outstanding)
        f16x8 rg[DEPTH][4];
        #pragma unroll
        for (int p = 0; p < DEPTH; ++p)
            #pragma unroll
            for (int j = 0; j < 4; ++j)
                asm volatile("global_load_dwordx4 %0, %1, off offset:%2"
                             : "=v"(rg[p][j]) : "v"(wb[j]), "n"(p * 64) : "memory");

        // af double buffer: k-step 0 preloaded (LDS, lgkm-tracked by compiler)
        f16x8 af[2][2];
        #pragma unroll
        for (int i = 0; i < 2; ++i)
            af[0][i] = *(const f16x8*)&act[cur][i * 16 + m15][q * 8];

        #pragma unroll
        for (int kt = 0; kt < 16; ++kt) {
            const int sl = kt % DEPTH, ab = kt & 1;
            if (kt + 1 < 16) {
                #pragma unroll
                for (int i = 0; i < 2; ++i)
                    af[ab ^ 1][i] = *(const f16x8*)&act[cur][i * 16 + m15][(kt + 1) * 32 + q * 8];
            }
            // wait until this slot's 4 loads are done (keep the rest in flight)
            {
                const int inflight = 4 * (((kt + DEPTH) < 16 ? (kt + DEPTH) : 16) - kt);
                asm volatile("s_waitcnt vmcnt(%4)"
                             : "+v"(rg[sl][0]), "+v"(rg[sl][1]),
                               "+v"(rg[sl][2]), "+v"(rg[sl][3])
                             : "n"(inflight - 4));
            }
            #pragma unroll
            for (int i = 0; i < 2; ++i)
                #pragma unroll
                for (int j = 0; j < 4; ++j)
                    acc[i][j] = __builtin_amdgcn_mfma_f32_16x16x32_f16(af[ab][i], rg[sl][j], acc[i][j], 0, 0, 0);
            // refill the slot just consumed with k-step kt+DEPTH
            if (kt + DEPTH < 16) {
                #pragma unroll
                for (int j = 0; j < 4; ++j)
                    asm volatile("global_load_dwordx4 %0, %1, off offset:%2"
                                 : "=v"(rg[sl][j]) : "v"(wb[j]), "n"((kt + DEPTH) * 64) : "memory");
            }
        }

        // epilogue (C/D layout col=lane&15, row=quad*4+reg): gelu -> act[nxt]
        float bcol[4];
        #pragma unroll
        for (int j = 0; j < 4; ++j) bcol[j] = bias[ncol0 + j * 16 + m15];
        #pragma unroll
        for (int i = 0; i < 2; ++i)
            #pragma unroll
            for (int r = 0; r < 4; ++r) {
                int row = i * 16 + q * 4 + r;
                #pragma unroll
                for (int j = 0; j < 4; ++j)
                    act[nxt][row][ncol0 + j * 16 + m15] = (f16)gelu_f(acc[i][j][r] + bcol[j]);
            }
        __syncthreads();

        // anchor layers: spill stripe to global (row-local; same block reads back)
        int ai = (L == 1) ? 0 : (L == 4) ? 1 : (L == 9) ? 2 : -1;
        if (ai >= 0) {
            f16* dst = (ai == 0 ? Anc0 : ai == 1 ? Anc1 : Anc2) + (size_t)row0 * C_;
            for (int ch = tid; ch < 32 * 64; ch += NTHR) {
                int r = ch >> 6, c8 = (ch & 63) << 3;
                *(f16x8*)&dst[(size_t)r * C_ + c8] = *(const f16x8*)&act[nxt][r][c8];
            }
        }

        int t = (L == 11) ? 0 : (L == 14) ? 1 : (L == 17) ? 2 : -1;
        if (t >= 0) {
            // pool partials: this stripe spans <=2 batches
            {
                int c = tid;                         // NTHR == C_
                int b0 = row0 / HW_;
                int rs = (b0 + 1) * HW_ - row0; if (rs > 32) rs = 32;
                float s0 = 0.f, s1 = 0.f;
                for (int r = 0; r < rs; ++r)  s0 += (float)act[nxt][r][c];
                for (int r = rs; r < 32; ++r) s1 += (float)act[nxt][r][c];
                atomicAdd(&pooled[(size_t)(t * B_ + b0) * C_ + c], s0);
                if (rs < 32) atomicAdd(&pooled[(size_t)(t * B_ + b0 + 1) * C_ + c], s1);
            }
            grid_barrier(cnt, rel, ++epoch);

            // gate MLP + softmax: blocks 0..31, one batch each
            if (blk < B_) {
                int b = blk;
                spG[tid] = pooled[(size_t)(t * B_ + b) * C_ + tid] * (1.f / 196.f);
                __syncthreads();
                if (tid < HID_) {
                    const float* w = fc1w + (size_t)t * C_ * HID_ + tid;
                    float s = fc1b[t * HID_ + tid];
                    for (int c = 0; c < C_; ++c) s += spG[c] * w[(size_t)c * HID_];
                    shG[tid] = gelu_f(s);
                }
                __syncthreads();
                {
                    int c = tid;
                    const float* w2 = fc2w + (size_t)t * HID_ * (3 * C_) + c;
                    float l0 = fc2b[t * 3 * C_ + c];
                    float l1 = fc2b[t * 3 * C_ + C_ + c];
                    float l2 = fc2b[t * 3 * C_ + 2 * C_ + c];
                    for (int j = 0; j < HID_; ++j) {
                        float h = shG[j];
                        const float* rw = w2 + (size_t)j * 3 * C_;
                        l0 += h * rw[0]; l1 += h * rw[C_]; l2 += h * rw[2 * C_];
                    }
                    float m = fmaxf(l0, fmaxf(l1, l2));
                    float e0 = expf(l0 - m), e1 = expf(l1 - m), e2 = expf(l2 - m);
                    float inv = 1.f / (e0 + e1 + e2);
                    gates[(size_t)b * 3 * C_ + c]          = e0 * inv;
                    gates[(size_t)b * 3 * C_ + C_ + c]     = e1 * inv;
                    gates[(size_t)b * 3 * C_ + 2 * C_ + c] = e2 * inv;
                }
            }
            grid_barrier(cnt, rel, ++epoch);

            // routed add (row-local): act[nxt] += gamma * sum_a g[b,a,c]*anchor
            {
                float gamma = gammas[t];
                const f16* a0 = Anc0 + (size_t)row0 * C_;
                const f16* a1 = Anc1 + (size_t)row0 * C_;
                const f16* a2 = Anc2 + (size_t)row0 * C_;
                for (int ch = tid; ch < 32 * 64; ch += NTHR) {
                    int r = ch >> 6, c8 = (ch & 63) << 3;
                    int b = (row0 + r) / HW_;
                    const float* g = gates + (size_t)b * 3 * C_ + c8;
                    f16x8 xv = *(const f16x8*)&act[nxt][r][c8];
                    f16x8 v0 = *(const f16x8*)&a0[(size_t)r * C_ + c8];
                    f16x8 v1 = *(const f16x8*)&a1[(size_t)r * C_ + c8];
                    f16x8 v2 = *(const f16x8*)&a2[(size_t)r * C_ + c8];
                    float rr[8];
                    #pragma unroll
                    for (int e = 0; e < 8; ++e)
                        rr[e] = (float)xv[e] + gamma * (g[e] * (float)v0[e]
                              + g[C_ + e] * (float)v1[e] + g[2 * C_ + e] * (float)v2[e]);
                    if (t == 2) {
                        size_t o = (size_t)(row0 + r) * C_ + c8;
                        *(float4*)&out[o]     = make_float4(rr[0], rr[1], rr[2], rr[3]);
                        *(float4*)&out[o + 4] = make_float4(rr[4], rr[5], rr[6], rr[7]);
                    } else {
                        f16x8 o8;
                        #pragma unroll
                        for (int e = 0; e < 8; ++e) o8[e] = (f16)rr[e];
                        *(f16x8*)&act[nxt][r][c8] = o8;
                    }
                }
            }
            __syncthreads();
        }
    }
}

extern "C" void kernel_launch(void* const* d_in, const int* in_sizes, int n_in,
                              void* d_out, int out_size, void* d_ws, size_t ws_size,
                              hipStream_t stream)
{
    const float* x      = (const float*)d_in[0];
    const float* blockw = (const float*)d_in[1];
    const float* blockb = (const float*)d_in[2];
    const float* fc1w   = (const float*)d_in[3];
    const float* fc1b   = (const float*)d_in[4];
    const float* fc2w   = (const float*)d_in[5];
    const float* fc2b   = (const float*)d_in[6];
    const float* gammas = (const float*)d_in[7];
    float* out = (float*)d_out;

    const size_t NB = (size_t)M_ * C_;            // 3,211,264 elems
    f16* Wt   = (f16*)d_ws;                        // 9.44 MB
    f16* Anc0 = Wt + (size_t)NBLK * C_ * C_;       // 6.42 MB each
    f16* Anc1 = Anc0 + NB;
    f16* Anc2 = Anc1 + NB;
    float* pooled = (float*)(Anc2 + NB);           // [3][32][512]
    float* gates  = pooled + 3 * B_ * C_;          // [32][3][512]
    unsigned* cnt = (unsigned*)(gates + B_ * 3 * C_);
    unsigned* rel = cnt + 32;                      // separate cache line

    (void)hipMemsetAsync(pooled, 0, (size_t)(3 * B_ * C_ + B_ * 3 * C_) * 4 + 256, stream);
    conv_w<<<dim3(8, 8, NBLK), 256, 0, stream>>>(blockw, Wt);

    stage_persistent<<<NGRID, NTHR, 0, stream>>>(
        x, Wt, blockb, fc1w, fc1b, fc2w, fc2b, gammas,
        Anc0, Anc1, Anc2, pooled, gates, cnt, rel, out);
}